// Round 11
// baseline (177.705 us; speedup 1.0000x reference)
//
#include <hip/hip_runtime.h>
#include <hip/hip_bf16.h>

// ---------------- types ----------------
typedef __bf16 bf16_t;
typedef __bf16 bf16x8 __attribute__((ext_vector_type(8)));
typedef __bf16 bf16x4 __attribute__((ext_vector_type(4)));
typedef float  f32x4  __attribute__((ext_vector_type(4)));
typedef unsigned int uint;

#define MFMA(a,b,c) __builtin_amdgcn_mfma_f32_16x16x32_bf16((a),(b),(c),0,0,0)

// N tokens = 4096, C = 256, heads = 8, d = 32, 3C = 768, F = 1024
__device__ __forceinline__ size_t pidx(int n, int k, int K) {
  return (size_t)(n >> 4) * (K << 4) + ((k >> 3) << 7) + ((n & 15) << 3) + (k & 7);
}

__device__ __forceinline__ uint packbf2(float lo, float hi) {
  unsigned short a = __builtin_bit_cast(unsigned short, (bf16_t)lo);
  unsigned short b = __builtin_bit_cast(unsigned short, (bf16_t)hi);
  return (uint)a | ((uint)b << 16);
}

// ---------------- all four fp32 W[N][K] -> fragment-packed bf16 ----------------
__global__ __launch_bounds__(256) void cvt_pack_all(const float* __restrict__ w_qkv,
                                                    const float* __restrict__ w_proj,
                                                    const float* __restrict__ w_mlp1,
                                                    const float* __restrict__ w_mlp2,
                                                    bf16_t* __restrict__ wq, bf16_t* __restrict__ wp,
                                                    bf16_t* __restrict__ w1, bf16_t* __restrict__ w2) {
  int b = blockIdx.x;
  const float* src; bf16_t* dst; int t0, ksh;
  if (b < 96)       { src = w_qkv;  dst = wq; ksh = 5; t0 = b * 256; }
  else if (b < 128) { src = w_proj; dst = wp; ksh = 5; t0 = (b - 96) * 256; }
  else if (b < 256) { src = w_mlp1; dst = w1; ksh = 5; t0 = (b - 128) * 256; }
  else              { src = w_mlp2; dst = w2; ksh = 7; t0 = (b - 256) * 256; }
  int t = t0 + threadIdx.x;
  int n = t >> ksh, kb = t & ((1 << ksh) - 1);
  int K = 8 << ksh;
  const float* p = src + (size_t)n * K + kb * 8;
  float4 a = *(const float4*)p;
  float4 c = *(const float4*)(p + 4);
  bf16x8 o = {(bf16_t)a.x, (bf16_t)a.y, (bf16_t)a.z, (bf16_t)a.w,
              (bf16_t)c.x, (bf16_t)c.y, (bf16_t)c.z, (bf16_t)c.w};
  *(bf16x8*)(dst + (size_t)(n >> 4) * (K << 4) + kb * 128 + ((n & 15) << 3)) = o;
}

// ---------------- fused transpose_in + LayerNorm1 ----------------
__global__ __launch_bounds__(256) void fused_in(const float* __restrict__ x,
                                                const float* __restrict__ g,
                                                const float* __restrict__ bta,
                                                float* __restrict__ xl,
                                                bf16_t* __restrict__ xn) {
  __shared__ float tile[256][33];
  __shared__ float psum[8][32], psq[8][32], mu_s[32], rs_s[32];
  int t = threadIdx.x, n0 = blockIdx.x * 32;
  int lane32 = t & 31, grp = t >> 5;
#pragma unroll
  for (int it = 0; it < 32; ++it) {
    int c = grp + it * 8;
    tile[c][lane32] = x[(size_t)c * 4096 + n0 + lane32];
  }
  __syncthreads();
  float s = 0.f, sq = 0.f;
#pragma unroll
  for (int ci = 0; ci < 32; ++ci) {
    float v = tile[grp * 32 + ci][lane32];
    s += v; sq += v * v;
  }
  psum[grp][lane32] = s; psq[grp][lane32] = sq;
  __syncthreads();
  if (t < 32) {
    float S = 0.f, Q = 0.f;
#pragma unroll
    for (int p = 0; p < 8; ++p) { S += psum[p][t]; Q += psq[p][t]; }
    float mu = S * (1.0f / 256.0f);
    float var = Q * (1.0f / 256.0f) - mu * mu;
    mu_s[t] = mu; rs_s[t] = rsqrtf(var + 1e-5f);
  }
  __syncthreads();
  {
    float mu = mu_s[lane32], rs = rs_s[lane32];
    int row = n0 + lane32;
    bf16_t* op = xn + (size_t)(row >> 4) * 4096 + ((row & 15) << 3);
#pragma unroll
    for (int cc8 = 0; cc8 < 4; ++cc8) {
      int c0 = grp * 32 + cc8 * 8;
      bf16x8 o;
#pragma unroll
      for (int j = 0; j < 8; ++j) {
        int c = c0 + j;
        o[j] = (bf16_t)((tile[c][lane32] - mu) * rs * g[c] + bta[c]);
      }
      *(bf16x8*)(op + ((c0 >> 3) << 7)) = o;
    }
  }
#pragma unroll
  for (int it = 0; it < 4; ++it) {
    int j = grp + it * 8;
#pragma unroll
    for (int c0 = 0; c0 < 256; c0 += 32)
      xl[(size_t)(n0 + j) * 256 + c0 + lane32] = tile[c0 + lane32][j];
  }
}

// ---------------- generic C[M,N] = A[M,K] * W[N,K]^T (+epilogue) ----------
// EPI: 1 = bias+gelu(tanh) -> packed bf16, 3 = bias + qkv head-major scatter,
// 4 = fp32 K-split streaming partial (no bias).
template <int K, int EPI, int RPW, int KS = 1>
__global__ __launch_bounds__(256) void gemm_bt(const bf16_t* __restrict__ A,
                                               const bf16_t* __restrict__ W,
                                               const float* __restrict__ bias,
                                               void* __restrict__ outp, int ldn) {
  constexpr int RB = RPW / 16;
  constexpr int KLEN = K / KS;
  int w = threadIdx.x >> 6, lane = threadIdx.x & 63;
  int quad = lane >> 4, idx = lane & 15;
  int row0 = blockIdx.x * (4 * RPW) + w * RPW;
  int col0 = blockIdx.y * 64;
  int kb0 = (KS > 1) ? blockIdx.z * KLEN : 0;
  f32x4 acc[RB][4];
#pragma unroll
  for (int rb = 0; rb < RB; ++rb)
#pragma unroll
    for (int nb = 0; nb < 4; ++nb) acc[rb][nb] = (f32x4){0.f, 0.f, 0.f, 0.f};
  const bf16_t* abase = A + (size_t)(row0 >> 4) * (K << 4) + quad * 128 + idx * 8;
  const bf16_t* wbase = W + (size_t)(col0 >> 4) * (K << 4) + quad * 128 + idx * 8;
#pragma unroll 4
  for (int k0 = kb0; k0 < kb0 + KLEN; k0 += 32) {
    bf16x8 a[RB];
#pragma unroll
    for (int rb = 0; rb < RB; ++rb)
      a[rb] = *(const bf16x8*)(abase + (size_t)rb * (K << 4) + k0 * 16);
#pragma unroll
    for (int nb = 0; nb < 4; ++nb) {
      bf16x8 b = *(const bf16x8*)(wbase + (size_t)nb * (K << 4) + k0 * 16);
#pragma unroll
      for (int rb = 0; rb < RB; ++rb) acc[rb][nb] = MFMA(a[rb], b, acc[rb][nb]);
    }
  }
#pragma unroll
  for (int nb = 0; nb < 4; ++nb) {
    int c = col0 + nb * 16 + idx;
    float bv = (EPI == 4) ? 0.f : bias[c];
#pragma unroll
    for (int rb = 0; rb < RB; ++rb)
#pragma unroll
      for (int r = 0; r < 4; ++r) {
        int rr = row0 + rb * 16 + quad * 4 + r;
        float v = acc[rb][nb][r] + bv;
        if constexpr (EPI == 1) {
          float z = v * (0.7978845608f + 0.0356774081f * v * v);
          float t = __builtin_amdgcn_exp2f(z * 2.885390082f);
          float th = 1.f - 2.f * __builtin_amdgcn_rcpf(t + 1.f);
          v = 0.5f * v * (1.f + th);
          ((bf16_t*)outp)[pidx(rr, c, ldn)] = (bf16_t)v;
        } else if constexpr (EPI == 4) {
          ((float*)outp)[((size_t)blockIdx.z * 4096 + rr) * ldn + c] = v;
        } else {
          bf16_t* qh = (bf16_t*)outp;
          bf16_t* kh = qh + 1048576;
          bf16_t* vp = kh + 1048576;
          if (c < 256) {
            qh[(size_t)(c >> 5) * 131072 + rr * 32 + (c & 31)] = (bf16_t)v;
          } else if (c < 512) {
            kh[(size_t)((c - 256) >> 5) * 131072 + rr * 32 + (c & 31)] = (bf16_t)v;
          } else {
            vp[(size_t)((c - 512) >> 5) * 131072 + (rr >> 5) * 1024 + (c & 31) * 32 + (rr & 31)] = (bf16_t)v;
          }
        }
      }
  }
}

// ---------------- flash attention: pipelined, SPLIT=4, full-line stores ----------
// h in LOW 3 bits => XCD = h: each XCD's K/V working set = one head = 0.5MB,
// L2-resident (was 4MB = full L2, thrashing -> FETCH 24MB). Safe vs R6's false
// sharing because packed o_part gives each (n,h) a private 64B line, one writer.
#define SPLIT 4
__global__ __launch_bounds__(256, 4) void attn_split(const bf16_t* __restrict__ qkvh,
                                                     uint* __restrict__ o_part,
                                                     float* __restrict__ l_part) {
  __shared__ bf16_t P[2][4][32][72];  // 36KB (2 buffers)
  int w = threadIdx.x >> 6, lane = threadIdx.x & 63;
  int quad = lane >> 4, idx = lane & 15;
  int h  = blockIdx.x & 7;           // XCD affinity
  int qt = (blockIdx.x >> 3) & 31;
  int sp = blockIdx.x >> 8;
  int qrow = qt * 128 + w * 32;
  const bf16_t* qh = qkvh + (size_t)h * 131072;
  const bf16_t* kh = qh + 8 * 131072;
  const bf16_t* vp = kh + 8 * 131072;
  const float cs = 0.25503518f;  // log2(e)/sqrt(32)
  bf16x8 qr0 = *(const bf16x8*)(qh + (size_t)(qrow + idx) * 32 + quad * 8);
  bf16x8 qr1 = *(const bf16x8*)(qh + (size_t)(qrow + 16 + idx) * 32 + quad * 8);
  bf16x8 qf0, qf1;
#pragma unroll
  for (int j = 0; j < 8; ++j) {
    qf0[j] = (bf16_t)((float)qr0[j] * cs);
    qf1[j] = (bf16_t)((float)qr1[j] * cs);
  }
  float ls0 = 0.f, ls1 = 0.f;
  f32x4 o00 = {0.f,0.f,0.f,0.f}, o01 = {0.f,0.f,0.f,0.f};
  f32x4 o10 = {0.f,0.f,0.f,0.f}, o11 = {0.f,0.f,0.f,0.f};
  const f32x4 zero = {0.f,0.f,0.f,0.f};
  int kbase = sp * 1024;

  bf16x8 kf[4];
#pragma unroll
  for (int kb = 0; kb < 4; ++kb)
    kf[kb] = *(const bf16x8*)(kh + (size_t)(kbase + kb * 16 + idx) * 32 + quad * 8);

  // prologue: stage tile 0 into LDS[0]
#pragma unroll
  for (int kb = 0; kb < 4; ++kb) {
    f32x4 s0 = MFMA(kf[kb], qf0, zero);
    f32x4 s1 = MFMA(kf[kb], qf1, zero);
    float a0 = __builtin_amdgcn_exp2f(s0[0]), a1 = __builtin_amdgcn_exp2f(s0[1]);
    float a2 = __builtin_amdgcn_exp2f(s0[2]), a3 = __builtin_amdgcn_exp2f(s0[3]);
    float b0 = __builtin_amdgcn_exp2f(s1[0]), b1 = __builtin_amdgcn_exp2f(s1[1]);
    float b2 = __builtin_amdgcn_exp2f(s1[2]), b3 = __builtin_amdgcn_exp2f(s1[3]);
    ls0 += (a0 + a1) + (a2 + a3);
    ls1 += (b0 + b1) + (b2 + b3);
    bf16x4 pk0 = {(bf16_t)a0, (bf16_t)a1, (bf16_t)a2, (bf16_t)a3};
    bf16x4 pk1 = {(bf16_t)b0, (bf16_t)b1, (bf16_t)b2, (bf16_t)b3};
    *(bf16x4*)&P[0][w][idx][kb * 16 + quad * 4] = pk0;
    *(bf16x4*)&P[0][w][16 + idx][kb * 16 + quad * 4] = pk1;
  }
  // load K(1)
#pragma unroll
  for (int kb = 0; kb < 4; ++kb)
    kf[kb] = *(const bf16x8*)(kh + (size_t)(kbase + 64 + kb * 16 + idx) * 32 + quad * 8);

#pragma unroll 2
  for (int t = 0; t < 16; ++t) {
    int par = t & 1;
    int k0 = kbase + t * 64;
    bf16x8 pa00 = *(const bf16x8*)&P[par][w][idx][quad * 8];
    bf16x8 pa01 = *(const bf16x8*)&P[par][w][idx][32 + quad * 8];
    bf16x8 pa10 = *(const bf16x8*)&P[par][w][16 + idx][quad * 8];
    bf16x8 pa11 = *(const bf16x8*)&P[par][w][16 + idx][32 + quad * 8];
    const bf16_t* vt = vp + (size_t)(k0 >> 5) * 1024 + quad * 8;
    bf16x8 vv0 = *(const bf16x8*)(vt + idx * 32);
    bf16x8 vv1 = *(const bf16x8*)(vt + (idx + 16) * 32);
    bf16x8 vv2 = *(const bf16x8*)(vt + 1024 + idx * 32);
    bf16x8 vv3 = *(const bf16x8*)(vt + 1024 + (idx + 16) * 32);
    int kn = kbase + ((t + 2) & 15) * 64;
    bf16x8 kfn[4];
#pragma unroll
    for (int kb = 0; kb < 4; ++kb)
      kfn[kb] = *(const bf16x8*)(kh + (size_t)(kn + kb * 16 + idx) * 32 + quad * 8);
    if (t < 15) {
#pragma unroll
      for (int kb = 0; kb < 4; ++kb) {
        f32x4 s0 = MFMA(kf[kb], qf0, zero);
        f32x4 s1 = MFMA(kf[kb], qf1, zero);
        float a0 = __builtin_amdgcn_exp2f(s0[0]), a1 = __builtin_amdgcn_exp2f(s0[1]);
        float a2 = __builtin_amdgcn_exp2f(s0[2]), a3 = __builtin_amdgcn_exp2f(s0[3]);
        float b0 = __builtin_amdgcn_exp2f(s1[0]), b1 = __builtin_amdgcn_exp2f(s1[1]);
        float b2 = __builtin_amdgcn_exp2f(s1[2]), b3 = __builtin_amdgcn_exp2f(s1[3]);
        ls0 += (a0 + a1) + (a2 + a3);
        ls1 += (b0 + b1) + (b2 + b3);
        bf16x4 pk0 = {(bf16_t)a0, (bf16_t)a1, (bf16_t)a2, (bf16_t)a3};
        bf16x4 pk1 = {(bf16_t)b0, (bf16_t)b1, (bf16_t)b2, (bf16_t)b3};
        *(bf16x4*)&P[1 - par][w][idx][kb * 16 + quad * 4] = pk0;
        *(bf16x4*)&P[1 - par][w][16 + idx][kb * 16 + quad * 4] = pk1;
      }
    }
    o00 = MFMA(pa00, vv0, o00);
    o01 = MFMA(pa00, vv1, o01);
    o10 = MFMA(pa10, vv0, o10);
    o11 = MFMA(pa10, vv1, o11);
    o00 = MFMA(pa01, vv2, o00);
    o01 = MFMA(pa01, vv3, o01);
    o10 = MFMA(pa11, vv2, o10);
    o11 = MFMA(pa11, vv3, o11);
#pragma unroll
    for (int kb = 0; kb < 4; ++kb) kf[kb] = kfn[kb];
  }
  ls0 += __shfl_xor(ls0, 16); ls0 += __shfl_xor(ls0, 32);
  ls1 += __shfl_xor(ls1, 16); ls1 += __shfl_xor(ls1, 32);
  if (quad == 0) {
    l_part[((size_t)sp * 8 + h) * 4096 + qrow + idx]      = ls0;
    l_part[((size_t)sp * 8 + h) * 4096 + qrow + 16 + idx] = ls1;
  }
#pragma unroll
  for (int r = 0; r < 4; ++r) {
    int n0 = qrow + quad * 4 + r;
    o_part[(((size_t)sp * 4096 + n0) * 8 + h) * 16 + idx] = packbf2(o00[r], o01[r]);
    int n1 = n0 + 16;
    o_part[(((size_t)sp * 4096 + n1) * 8 + h) * 16 + idx] = packbf2(o10[r], o11[r]);
  }
}

// ---------------- combine split partials -> packed attn ----------------
__global__ __launch_bounds__(256) void attn_norm(const uint* __restrict__ o_part,
                                                 const float* __restrict__ l_part,
                                                 bf16_t* __restrict__ attn) {
  int t = blockIdx.x * 256 + threadIdx.x;  // 131072 threads
  int j0 = (t & 3) * 4;
  int h  = (t >> 2) & 7;
  int n  = t >> 5;
  float l = 0.f;
#pragma unroll
  for (int s = 0; s < SPLIT; ++s) l += l_part[((size_t)s * 8 + h) * 4096 + n];
  float inv = 1.0f / l;
  float alo[4] = {0.f,0.f,0.f,0.f}, ahi[4] = {0.f,0.f,0.f,0.f};
#pragma unroll
  for (int s = 0; s < SPLIT; ++s) {
    const uint* p = o_part + (((size_t)s * 4096 + n) * 8 + h) * 16 + j0;
    uint4 v = *(const uint4*)p;
    uint vv[4] = {v.x, v.y, v.z, v.w};
#pragma unroll
    for (int jj = 0; jj < 4; ++jj) {
      alo[jj] += __builtin_bit_cast(float, vv[jj] << 16);
      ahi[jj] += __builtin_bit_cast(float, vv[jj] & 0xffff0000u);
    }
  }
  bf16x4 lo = {(bf16_t)(alo[0] * inv), (bf16_t)(alo[1] * inv),
               (bf16_t)(alo[2] * inv), (bf16_t)(alo[3] * inv)};
  bf16x4 hi = {(bf16_t)(ahi[0] * inv), (bf16_t)(ahi[1] * inv),
               (bf16_t)(ahi[2] * inv), (bf16_t)(ahi[3] * inv)};
  int k1 = h * 32 + j0;
  int k2 = k1 + 16;
  *(bf16x4*)(attn + (size_t)(n >> 4) * 4096 + ((k1 >> 3) << 7) + ((n & 15) << 3) + (k1 & 7)) = lo;
  *(bf16x4*)(attn + (size_t)(n >> 4) * 4096 + ((k2 >> 3) << 7) + ((n & 15) << 3) + (k2 & 7)) = hi;
}

// ---------------- combine proj K-split partials + residual + bias + LN2 --------
__global__ __launch_bounds__(256) void combine_ln(const float* __restrict__ pp,
                                                  const float* __restrict__ xl,
                                                  const float* __restrict__ bias,
                                                  const float* __restrict__ g,
                                                  const float* __restrict__ bta,
                                                  float* __restrict__ xl2,
                                                  bf16_t* __restrict__ xn2) {
  int row  = blockIdx.x * 4 + (threadIdx.x >> 6);
  int lane = threadIdx.x & 63;
  size_t ri = (size_t)row * 64 + lane;
  float4 rr = ((const float4*)xl)[ri];
  float4 bb = ((const float4*)bias)[lane];
  float4 v = {rr.x + bb.x, rr.y + bb.y, rr.z + bb.z, rr.w + bb.w};
#pragma unroll
  for (int s = 0; s < 2; ++s) {
    float4 p = ((const float4*)pp)[ri + (size_t)s * 4096 * 64];
    v.x += p.x; v.y += p.y; v.z += p.z; v.w += p.w;
  }
  ((float4*)xl2)[ri] = v;
  float s  = v.x + v.y + v.z + v.w;
  float sq = v.x * v.x + v.y * v.y + v.z * v.z + v.w * v.w;
#pragma unroll
  for (int off = 32; off; off >>= 1) {
    s  += __shfl_xor(s, off);
    sq += __shfl_xor(sq, off);
  }
  float mu  = s * (1.0f / 256.0f);
  float var = sq * (1.0f / 256.0f) - mu * mu;
  float rs  = rsqrtf(var + 1e-5f);
  float4 gg = ((const float4*)g)[lane];
  float4 b2 = ((const float4*)bta)[lane];
  bf16x4 o = {(bf16_t)((v.x - mu) * rs * gg.x + b2.x),
              (bf16_t)((v.y - mu) * rs * gg.y + b2.y),
              (bf16_t)((v.z - mu) * rs * gg.z + b2.z),
              (bf16_t)((v.w - mu) * rs * gg.w + b2.w)};
  int k = lane * 4;
  *(bf16x4*)(xn2 + (size_t)(row >> 4) * 4096 + ((k >> 3) << 7) + ((row & 15) << 3) + (k & 7)) = o;
}

// ---------------- combine mlp2 K-split partials + residual + bias + transpose --
__global__ __launch_bounds__(256) void combine_transpose(const float* __restrict__ mp,
                                                         const float* __restrict__ xl2,
                                                         const float* __restrict__ bias,
                                                         float* __restrict__ dst) {
  __shared__ float tile[32][33];
  int n0 = blockIdx.x * 32, c0 = blockIdx.y * 32;
  int a = threadIdx.x & 31, b = threadIdx.x >> 5;
  float bv = bias[c0 + a];
#pragma unroll
  for (int i = 0; i < 4; ++i) {
    int n = b + i * 8;
    size_t base = (size_t)(n0 + n) * 256 + c0 + a;
    float v = xl2[base] + bv;
#pragma unroll
    for (int s = 0; s < 4; ++s) v += mp[(size_t)s * 1048576 + base];
    tile[a][n] = v;
  }
  __syncthreads();
#pragma unroll
  for (int i = 0; i < 4; ++i) {
    int c = b + i * 8;
    dst[(size_t)(c0 + c) * 4096 + n0 + a] = tile[c][a];
  }
}

// ---------------- launch ----------------
extern "C" void kernel_launch(void* const* d_in, const int* in_sizes, int n_in,
                              void* d_out, int out_size, void* d_ws, size_t ws_size,
                              hipStream_t stream) {
  const float* x      = (const float*)d_in[0];
  const float* ln1_g  = (const float*)d_in[1];
  const float* ln1_b  = (const float*)d_in[2];
  const float* w_qkv  = (const float*)d_in[3];
  const float* b_qkv  = (const float*)d_in[4];
  const float* w_proj = (const float*)d_in[5];
  const float* b_proj = (const float*)d_in[6];
  const float* ln2_g  = (const float*)d_in[7];
  const float* ln2_b  = (const float*)d_in[8];
  const float* w_mlp1 = (const float*)d_in[9];
  const float* b_mlp1 = (const float*)d_in[10];
  const float* w_mlp2 = (const float*)d_in[11];
  const float* b_mlp2 = (const float*)d_in[12];

  char* ws = (char*)d_ws;  // >= 40 MB verified
  // LIVENESS: weights at [32,33.5) outlive all partial buffers (which end at 32).
  bf16_t* qkvh   = (bf16_t*)(ws + 0);             // [0,6)   qh|kh|vp
  float*  xl     = (float*)(ws + (6u << 20));     // [6,10)  fp32 residual1
  bf16_t* xn     = (bf16_t*)(ws + (10u << 20));   // [10,12) packed LN1 out
  uint*   o_part = (uint*)(ws + (12u << 20));     // [12,20) packed attn partials
  bf16_t* attn   = (bf16_t*)(ws + (20u << 20));   // [20,22) packed
  float*  pp     = (float*)(ws + (24u << 20));    // [24,32) proj partials (2x4MB)
  float*  xl2    = (float*)(ws + (10u << 20));    // [10,14) (xn + o_part[12,14) dead)
  bf16_t* xn2    = (bf16_t*)(ws + (14u << 20));   // [14,16) (o_part dead)
  bf16_t* h1     = (bf16_t*)(ws + 0);             // [0,8)   (qkvh, xl dead)
  float*  mp     = (float*)(ws + (16u << 20));    // [16,32) mlp2 partials (4x4MB)
  bf16_t* wq     = (bf16_t*)(ws + (32u << 20));   // [32,33.5) packed weights
  bf16_t* wp     = wq + 196608;
  bf16_t* w1     = wp + 65536;
  bf16_t* w2     = w1 + 262144;
  float*  l_part = (float*)(ws + (34304u << 10)); // [33.5,34) 512KB

  cvt_pack_all<<<384, 256, 0, stream>>>(w_qkv, w_proj, w_mlp1, w_mlp2, wq, wp, w1, w2);
  fused_in<<<128, 256, 0, stream>>>(x, ln1_g, ln1_b, xl, xn);

  // qkv: RPW=32 (8 MFMA : 6 loads per k-step), grid 384 blocks
  gemm_bt<256, 3, 32><<<dim3(32, 12), 256, 0, stream>>>(xn, wq, b_qkv, qkvh, 768);
  attn_split<<<256 * SPLIT, 256, 0, stream>>>(qkvh, o_part, l_part);
  attn_norm<<<512, 256, 0, stream>>>(o_part, l_part, attn);

  // proj: K-split x2 streaming fp32 partials (512 blocks)
  gemm_bt<256, 4, 16, 2><<<dim3(64, 4, 2), 256, 0, stream>>>(attn, wp, nullptr, pp, 256);
  combine_ln<<<1024, 256, 0, stream>>>(pp, xl, b_proj, ln2_g, ln2_b, xl2, xn2);

  // mlp1: RPW=32, grid 512 blocks
  gemm_bt<256, 1, 32><<<dim3(32, 16), 256, 0, stream>>>(xn2, w1, b_mlp1, h1, 1024);
  // mlp2: RPW=32 + K-split x4, grid 512 blocks
  gemm_bt<1024, 4, 32, 4><<<dim3(32, 4, 4), 256, 0, stream>>>(h1, w2, nullptr, mp, 256);
  combine_transpose<<<dim3(128, 8), 256, 0, stream>>>(mp, xl2, b_mlp2, (float*)d_out);
}

// Round 12
// 166.374 us; speedup vs baseline: 1.0681x; 1.0681x over previous
//
#include <hip/hip_runtime.h>
#include <hip/hip_bf16.h>

// ---------------- types ----------------
typedef __bf16 bf16_t;
typedef __bf16 bf16x8 __attribute__((ext_vector_type(8)));
typedef __bf16 bf16x4 __attribute__((ext_vector_type(4)));
typedef float  f32x4  __attribute__((ext_vector_type(4)));
typedef unsigned int uint;

#define MFMA(a,b,c) __builtin_amdgcn_mfma_f32_16x16x32_bf16((a),(b),(c),0,0,0)

// N tokens = 4096, C = 256, heads = 8, d = 32, 3C = 768, F = 1024
__device__ __forceinline__ size_t pidx(int n, int k, int K) {
  return (size_t)(n >> 4) * (K << 4) + ((k >> 3) << 7) + ((n & 15) << 3) + (k & 7);
}

__device__ __forceinline__ uint packbf2(float lo, float hi) {
  unsigned short a = __builtin_bit_cast(unsigned short, (bf16_t)lo);
  unsigned short b = __builtin_bit_cast(unsigned short, (bf16_t)hi);
  return (uint)a | ((uint)b << 16);
}

// ---------------- prep: weight cvt_pack (blocks 0-383) + transpose_in+LN1 (384-511)
__global__ __launch_bounds__(256) void prep(const float* __restrict__ w_qkv,
                                            const float* __restrict__ w_proj,
                                            const float* __restrict__ w_mlp1,
                                            const float* __restrict__ w_mlp2,
                                            bf16_t* __restrict__ wq, bf16_t* __restrict__ wp,
                                            bf16_t* __restrict__ w1, bf16_t* __restrict__ w2,
                                            const float* __restrict__ x,
                                            const float* __restrict__ g,
                                            const float* __restrict__ bta,
                                            float* __restrict__ xl,
                                            bf16_t* __restrict__ xn) {
  __shared__ float tile[256][33];
  __shared__ float psum[8][32], psq[8][32], mu_s[32], rs_s[32];
  int b = blockIdx.x;
  if (b < 384) {  // ---- weight convert+pack ----
    const float* src; bf16_t* dst; int t0, ksh;
    if (b < 96)       { src = w_qkv;  dst = wq; ksh = 5; t0 = b * 256; }
    else if (b < 128) { src = w_proj; dst = wp; ksh = 5; t0 = (b - 96) * 256; }
    else if (b < 256) { src = w_mlp1; dst = w1; ksh = 5; t0 = (b - 128) * 256; }
    else              { src = w_mlp2; dst = w2; ksh = 7; t0 = (b - 256) * 256; }
    int t = t0 + threadIdx.x;
    int n = t >> ksh, kb = t & ((1 << ksh) - 1);
    int K = 8 << ksh;
    const float* p = src + (size_t)n * K + kb * 8;
    float4 a = *(const float4*)p;
    float4 c = *(const float4*)(p + 4);
    bf16x8 o = {(bf16_t)a.x, (bf16_t)a.y, (bf16_t)a.z, (bf16_t)a.w,
                (bf16_t)c.x, (bf16_t)c.y, (bf16_t)c.z, (bf16_t)c.w};
    *(bf16x8*)(dst + (size_t)(n >> 4) * (K << 4) + kb * 128 + ((n & 15) << 3)) = o;
    return;
  }
  // ---- fused transpose_in + LayerNorm1 ----
  int t = threadIdx.x, n0 = (b - 384) * 32;
  int lane32 = t & 31, grp = t >> 5;
#pragma unroll
  for (int it = 0; it < 32; ++it) {
    int c = grp + it * 8;
    tile[c][lane32] = x[(size_t)c * 4096 + n0 + lane32];
  }
  __syncthreads();
  float s = 0.f, sq = 0.f;
#pragma unroll
  for (int ci = 0; ci < 32; ++ci) {
    float v = tile[grp * 32 + ci][lane32];
    s += v; sq += v * v;
  }
  psum[grp][lane32] = s; psq[grp][lane32] = sq;
  __syncthreads();
  if (t < 32) {
    float S = 0.f, Q = 0.f;
#pragma unroll
    for (int p = 0; p < 8; ++p) { S += psum[p][t]; Q += psq[p][t]; }
    float mu = S * (1.0f / 256.0f);
    float var = Q * (1.0f / 256.0f) - mu * mu;
    mu_s[t] = mu; rs_s[t] = rsqrtf(var + 1e-5f);
  }
  __syncthreads();
  {
    float mu = mu_s[lane32], rs = rs_s[lane32];
    int row = n0 + lane32;
    bf16_t* op = xn + (size_t)(row >> 4) * 4096 + ((row & 15) << 3);
#pragma unroll
    for (int cc8 = 0; cc8 < 4; ++cc8) {
      int c0 = grp * 32 + cc8 * 8;
      bf16x8 o;
#pragma unroll
      for (int j = 0; j < 8; ++j) {
        int c = c0 + j;
        o[j] = (bf16_t)((tile[c][lane32] - mu) * rs * g[c] + bta[c]);
      }
      *(bf16x8*)(op + ((c0 >> 3) << 7)) = o;
    }
  }
#pragma unroll
  for (int it = 0; it < 4; ++it) {
    int j = grp + it * 8;
#pragma unroll
    for (int c0 = 0; c0 < 256; c0 += 32)
      xl[(size_t)(n0 + j) * 256 + c0 + lane32] = tile[c0 + lane32][j];
  }
}

// ---------------- generic C[M,N] = A[M,K] * W[N,K]^T (+epilogue) ----------
// EPI: 1 = bias+gelu(tanh) -> packed bf16, 3 = bias + qkv head-major scatter,
// 4 = fp32 K-split streaming partial (no bias).
template <int K, int EPI, int RPW, int KS = 1>
__global__ __launch_bounds__(256) void gemm_bt(const bf16_t* __restrict__ A,
                                               const bf16_t* __restrict__ W,
                                               const float* __restrict__ bias,
                                               void* __restrict__ outp, int ldn) {
  constexpr int RB = RPW / 16;
  constexpr int KLEN = K / KS;
  int w = threadIdx.x >> 6, lane = threadIdx.x & 63;
  int quad = lane >> 4, idx = lane & 15;
  int row0 = blockIdx.x * (4 * RPW) + w * RPW;
  int col0 = blockIdx.y * 64;
  int kb0 = (KS > 1) ? blockIdx.z * KLEN : 0;
  f32x4 acc[RB][4];
#pragma unroll
  for (int rb = 0; rb < RB; ++rb)
#pragma unroll
    for (int nb = 0; nb < 4; ++nb) acc[rb][nb] = (f32x4){0.f, 0.f, 0.f, 0.f};
  const bf16_t* abase = A + (size_t)(row0 >> 4) * (K << 4) + quad * 128 + idx * 8;
  const bf16_t* wbase = W + (size_t)(col0 >> 4) * (K << 4) + quad * 128 + idx * 8;
#pragma unroll 4
  for (int k0 = kb0; k0 < kb0 + KLEN; k0 += 32) {
    bf16x8 a[RB];
#pragma unroll
    for (int rb = 0; rb < RB; ++rb)
      a[rb] = *(const bf16x8*)(abase + (size_t)rb * (K << 4) + k0 * 16);
#pragma unroll
    for (int nb = 0; nb < 4; ++nb) {
      bf16x8 b = *(const bf16x8*)(wbase + (size_t)nb * (K << 4) + k0 * 16);
#pragma unroll
      for (int rb = 0; rb < RB; ++rb) acc[rb][nb] = MFMA(a[rb], b, acc[rb][nb]);
    }
  }
#pragma unroll
  for (int nb = 0; nb < 4; ++nb) {
    int c = col0 + nb * 16 + idx;
    float bv = (EPI == 4) ? 0.f : bias[c];
#pragma unroll
    for (int rb = 0; rb < RB; ++rb)
#pragma unroll
      for (int r = 0; r < 4; ++r) {
        int rr = row0 + rb * 16 + quad * 4 + r;
        float v = acc[rb][nb][r] + bv;
        if constexpr (EPI == 1) {
          float z = v * (0.7978845608f + 0.0356774081f * v * v);
          float t = __builtin_amdgcn_exp2f(z * 2.885390082f);
          float th = 1.f - 2.f * __builtin_amdgcn_rcpf(t + 1.f);
          v = 0.5f * v * (1.f + th);
          ((bf16_t*)outp)[pidx(rr, c, ldn)] = (bf16_t)v;
        } else if constexpr (EPI == 4) {
          ((float*)outp)[((size_t)blockIdx.z * 4096 + rr) * ldn + c] = v;
        } else {
          bf16_t* qh = (bf16_t*)outp;
          bf16_t* kh = qh + 1048576;
          bf16_t* vp = kh + 1048576;
          if (c < 256) {
            qh[(size_t)(c >> 5) * 131072 + rr * 32 + (c & 31)] = (bf16_t)v;
          } else if (c < 512) {
            kh[(size_t)((c - 256) >> 5) * 131072 + rr * 32 + (c & 31)] = (bf16_t)v;
          } else {
            vp[(size_t)((c - 512) >> 5) * 131072 + (rr >> 5) * 1024 + (c & 31) * 32 + (rr & 31)] = (bf16_t)v;
          }
        }
      }
  }
}

// ---------------- flash attention: R7 structure (measured best, <=43.5us) --------
// Single P buffer, non-pipelined, 16 MFMA/iter, VALU lsum, K prefetch 1 tile.
// + h in low 3 bits (XCD=h: per-XCD K/V = 0.5MB, L2-resident; FETCH 24->8.7 MB)
// + packbf2 full-line o_part stores (WRITE halves vs half-line bf16 stores).
#define SPLIT 4
__global__ __launch_bounds__(256, 4) void attn_split(const bf16_t* __restrict__ qkvh,
                                                     uint* __restrict__ o_part,
                                                     float* __restrict__ l_part) {
  __shared__ bf16_t P[4][32][72];  // 18KB, single buffer
  int w = threadIdx.x >> 6, lane = threadIdx.x & 63;
  int quad = lane >> 4, idx = lane & 15;
  int h  = blockIdx.x & 7;           // XCD affinity
  int qt = (blockIdx.x >> 3) & 31;
  int sp = blockIdx.x >> 8;
  int qrow = qt * 128 + w * 32;
  const bf16_t* qh = qkvh + (size_t)h * 131072;
  const bf16_t* kh = qh + 8 * 131072;
  const bf16_t* vp = kh + 8 * 131072;
  const float cs = 0.25503518f;  // log2(e)/sqrt(32)
  bf16x8 qr0 = *(const bf16x8*)(qh + (size_t)(qrow + idx) * 32 + quad * 8);
  bf16x8 qr1 = *(const bf16x8*)(qh + (size_t)(qrow + 16 + idx) * 32 + quad * 8);
  bf16x8 qf0, qf1;
#pragma unroll
  for (int j = 0; j < 8; ++j) {
    qf0[j] = (bf16_t)((float)qr0[j] * cs);
    qf1[j] = (bf16_t)((float)qr1[j] * cs);
  }
  float ls0 = 0.f, ls1 = 0.f;
  f32x4 o00 = {0.f,0.f,0.f,0.f}, o01 = {0.f,0.f,0.f,0.f};
  f32x4 o10 = {0.f,0.f,0.f,0.f}, o11 = {0.f,0.f,0.f,0.f};
  const f32x4 zero = {0.f,0.f,0.f,0.f};
  int kbase = sp * 1024;

  bf16x8 kf[4];
#pragma unroll
  for (int kb = 0; kb < 4; ++kb)
    kf[kb] = *(const bf16x8*)(kh + (size_t)(kbase + kb * 16 + idx) * 32 + quad * 8);

  for (int kt = 0; kt < 16; ++kt) {
    int k0 = kbase + kt * 64;
    int k1 = kbase + ((kt + 1) & 15) * 64;  // wrapped dummy on last iter
    const bf16_t* vt = vp + (size_t)(k0 >> 5) * 1024 + quad * 8;
    bf16x8 vv0 = *(const bf16x8*)(vt + idx * 32);
    bf16x8 vv1 = *(const bf16x8*)(vt + (idx + 16) * 32);
    bf16x8 vv2 = *(const bf16x8*)(vt + 1024 + idx * 32);
    bf16x8 vv3 = *(const bf16x8*)(vt + 1024 + (idx + 16) * 32);
    bf16x8 kfn[4];
#pragma unroll
    for (int kb = 0; kb < 4; ++kb)
      kfn[kb] = *(const bf16x8*)(kh + (size_t)(k1 + kb * 16 + idx) * 32 + quad * 8);
#pragma unroll
    for (int kb = 0; kb < 4; ++kb) {
      f32x4 s0 = MFMA(kf[kb], qf0, zero);
      f32x4 s1 = MFMA(kf[kb], qf1, zero);
      float a0 = __builtin_amdgcn_exp2f(s0[0]), a1 = __builtin_amdgcn_exp2f(s0[1]);
      float a2 = __builtin_amdgcn_exp2f(s0[2]), a3 = __builtin_amdgcn_exp2f(s0[3]);
      float b0 = __builtin_amdgcn_exp2f(s1[0]), b1 = __builtin_amdgcn_exp2f(s1[1]);
      float b2 = __builtin_amdgcn_exp2f(s1[2]), b3 = __builtin_amdgcn_exp2f(s1[3]);
      ls0 += (a0 + a1) + (a2 + a3);
      ls1 += (b0 + b1) + (b2 + b3);
      bf16x4 pk0 = {(bf16_t)a0, (bf16_t)a1, (bf16_t)a2, (bf16_t)a3};
      bf16x4 pk1 = {(bf16_t)b0, (bf16_t)b1, (bf16_t)b2, (bf16_t)b3};
      *(bf16x4*)&P[w][idx][kb * 16 + quad * 4] = pk0;
      *(bf16x4*)&P[w][16 + idx][kb * 16 + quad * 4] = pk1;
    }
#pragma unroll
    for (int kc = 0; kc < 2; ++kc) {
      bf16x8 pa0 = *(const bf16x8*)&P[w][idx][kc * 32 + quad * 8];
      bf16x8 pa1 = *(const bf16x8*)&P[w][16 + idx][kc * 32 + quad * 8];
      bf16x8 va = kc ? vv2 : vv0;
      bf16x8 vb = kc ? vv3 : vv1;
      o00 = MFMA(pa0, va, o00);
      o01 = MFMA(pa0, vb, o01);
      o10 = MFMA(pa1, va, o10);
      o11 = MFMA(pa1, vb, o11);
    }
#pragma unroll
    for (int kb = 0; kb < 4; ++kb) kf[kb] = kfn[kb];
  }
  ls0 += __shfl_xor(ls0, 16); ls0 += __shfl_xor(ls0, 32);
  ls1 += __shfl_xor(ls1, 16); ls1 += __shfl_xor(ls1, 32);
  if (quad == 0) {
    l_part[((size_t)sp * 8 + h) * 4096 + qrow + idx]      = ls0;
    l_part[((size_t)sp * 8 + h) * 4096 + qrow + 16 + idx] = ls1;
  }
  // full-line packed stores: uint32 = (bf16 d=idx) | (bf16 d=idx+16)<<16
#pragma unroll
  for (int r = 0; r < 4; ++r) {
    int n0 = qrow + quad * 4 + r;
    o_part[(((size_t)sp * 4096 + n0) * 8 + h) * 16 + idx] = packbf2(o00[r], o01[r]);
    int n1 = n0 + 16;
    o_part[(((size_t)sp * 4096 + n1) * 8 + h) * 16 + idx] = packbf2(o10[r], o11[r]);
  }
}

// ---------------- combine split partials -> packed attn ----------------
__global__ __launch_bounds__(256) void attn_norm(const uint* __restrict__ o_part,
                                                 const float* __restrict__ l_part,
                                                 bf16_t* __restrict__ attn) {
  int t = blockIdx.x * 256 + threadIdx.x;  // 131072 threads
  int j0 = (t & 3) * 4;
  int h  = (t >> 2) & 7;
  int n  = t >> 5;
  float l = 0.f;
#pragma unroll
  for (int s = 0; s < SPLIT; ++s) l += l_part[((size_t)s * 8 + h) * 4096 + n];
  float inv = 1.0f / l;
  float alo[4] = {0.f,0.f,0.f,0.f}, ahi[4] = {0.f,0.f,0.f,0.f};
#pragma unroll
  for (int s = 0; s < SPLIT; ++s) {
    const uint* p = o_part + (((size_t)s * 4096 + n) * 8 + h) * 16 + j0;
    uint4 v = *(const uint4*)p;
    uint vv[4] = {v.x, v.y, v.z, v.w};
#pragma unroll
    for (int jj = 0; jj < 4; ++jj) {
      alo[jj] += __builtin_bit_cast(float, vv[jj] << 16);
      ahi[jj] += __builtin_bit_cast(float, vv[jj] & 0xffff0000u);
    }
  }
  bf16x4 lo = {(bf16_t)(alo[0] * inv), (bf16_t)(alo[1] * inv),
               (bf16_t)(alo[2] * inv), (bf16_t)(alo[3] * inv)};
  bf16x4 hi = {(bf16_t)(ahi[0] * inv), (bf16_t)(ahi[1] * inv),
               (bf16_t)(ahi[2] * inv), (bf16_t)(ahi[3] * inv)};
  int k1 = h * 32 + j0;
  int k2 = k1 + 16;
  *(bf16x4*)(attn + (size_t)(n >> 4) * 4096 + ((k1 >> 3) << 7) + ((n & 15) << 3) + (k1 & 7)) = lo;
  *(bf16x4*)(attn + (size_t)(n >> 4) * 4096 + ((k2 >> 3) << 7) + ((n & 15) << 3) + (k2 & 7)) = hi;
}

// ---------------- combine proj K-split partials + residual + bias + LN2 --------
__global__ __launch_bounds__(256) void combine_ln(const float* __restrict__ pp,
                                                  const float* __restrict__ xl,
                                                  const float* __restrict__ bias,
                                                  const float* __restrict__ g,
                                                  const float* __restrict__ bta,
                                                  float* __restrict__ xl2,
                                                  bf16_t* __restrict__ xn2) {
  int row  = blockIdx.x * 4 + (threadIdx.x >> 6);
  int lane = threadIdx.x & 63;
  size_t ri = (size_t)row * 64 + lane;
  float4 rr = ((const float4*)xl)[ri];
  float4 bb = ((const float4*)bias)[lane];
  float4 v = {rr.x + bb.x, rr.y + bb.y, rr.z + bb.z, rr.w + bb.w};
#pragma unroll
  for (int s = 0; s < 2; ++s) {
    float4 p = ((const float4*)pp)[ri + (size_t)s * 4096 * 64];
    v.x += p.x; v.y += p.y; v.z += p.z; v.w += p.w;
  }
  ((float4*)xl2)[ri] = v;
  float s  = v.x + v.y + v.z + v.w;
  float sq = v.x * v.x + v.y * v.y + v.z * v.z + v.w * v.w;
#pragma unroll
  for (int off = 32; off; off >>= 1) {
    s  += __shfl_xor(s, off);
    sq += __shfl_xor(sq, off);
  }
  float mu  = s * (1.0f / 256.0f);
  float var = sq * (1.0f / 256.0f) - mu * mu;
  float rs  = rsqrtf(var + 1e-5f);
  float4 gg = ((const float4*)g)[lane];
  float4 b2 = ((const float4*)bta)[lane];
  bf16x4 o = {(bf16_t)((v.x - mu) * rs * gg.x + b2.x),
              (bf16_t)((v.y - mu) * rs * gg.y + b2.y),
              (bf16_t)((v.z - mu) * rs * gg.z + b2.z),
              (bf16_t)((v.w - mu) * rs * gg.w + b2.w)};
  int k = lane * 4;
  *(bf16x4*)(xn2 + (size_t)(row >> 4) * 4096 + ((k >> 3) << 7) + ((row & 15) << 3) + (k & 7)) = o;
}

// ---------------- combine mlp2 K-split partials + residual + bias + transpose --
__global__ __launch_bounds__(256) void combine_transpose(const float* __restrict__ mp,
                                                         const float* __restrict__ xl2,
                                                         const float* __restrict__ bias,
                                                         float* __restrict__ dst) {
  __shared__ float tile[32][33];
  int n0 = blockIdx.x * 32, c0 = blockIdx.y * 32;
  int a = threadIdx.x & 31, b = threadIdx.x >> 5;
  float bv = bias[c0 + a];
#pragma unroll
  for (int i = 0; i < 4; ++i) {
    int n = b + i * 8;
    size_t base = (size_t)(n0 + n) * 256 + c0 + a;
    float v = xl2[base] + bv;
#pragma unroll
    for (int s = 0; s < 4; ++s) v += mp[(size_t)s * 1048576 + base];
    tile[a][n] = v;
  }
  __syncthreads();
#pragma unroll
  for (int i = 0; i < 4; ++i) {
    int c = b + i * 8;
    dst[(size_t)(c0 + c) * 4096 + n0 + a] = tile[c][a];
  }
}

// ---------------- launch ----------------
extern "C" void kernel_launch(void* const* d_in, const int* in_sizes, int n_in,
                              void* d_out, int out_size, void* d_ws, size_t ws_size,
                              hipStream_t stream) {
  const float* x      = (const float*)d_in[0];
  const float* ln1_g  = (const float*)d_in[1];
  const float* ln1_b  = (const float*)d_in[2];
  const float* w_qkv  = (const float*)d_in[3];
  const float* b_qkv  = (const float*)d_in[4];
  const float* w_proj = (const float*)d_in[5];
  const float* b_proj = (const float*)d_in[6];
  const float* ln2_g  = (const float*)d_in[7];
  const float* ln2_b  = (const float*)d_in[8];
  const float* w_mlp1 = (const float*)d_in[9];
  const float* b_mlp1 = (const float*)d_in[10];
  const float* w_mlp2 = (const float*)d_in[11];
  const float* b_mlp2 = (const float*)d_in[12];

  char* ws = (char*)d_ws;  // >= 40 MB verified
  // LIVENESS: weights at [32,33.5) outlive all partial buffers (which end at 32).
  bf16_t* qkvh   = (bf16_t*)(ws + 0);             // [0,6)   qh|kh|vp
  float*  xl     = (float*)(ws + (6u << 20));     // [6,10)  fp32 residual1
  bf16_t* xn     = (bf16_t*)(ws + (10u << 20));   // [10,12) packed LN1 out
  uint*   o_part = (uint*)(ws + (12u << 20));     // [12,20) packed attn partials
  bf16_t* attn   = (bf16_t*)(ws + (20u << 20));   // [20,22) packed
  float*  pp     = (float*)(ws + (24u << 20));    // [24,32) proj partials (2x4MB)
  float*  xl2    = (float*)(ws + (10u << 20));    // [10,14) (xn + o_part[12,14) dead)
  bf16_t* xn2    = (bf16_t*)(ws + (14u << 20));   // [14,16) (o_part dead)
  bf16_t* h1     = (bf16_t*)(ws + 0);             // [0,8)   (qkvh, xl dead)
  float*  mp     = (float*)(ws + (16u << 20));    // [16,32) mlp2 partials (4x4MB)
  bf16_t* wq     = (bf16_t*)(ws + (32u << 20));   // [32,33.5) packed weights
  bf16_t* wp     = wq + 196608;
  bf16_t* w1     = wp + 65536;
  bf16_t* w2     = w1 + 262144;
  float*  l_part = (float*)(ws + (34304u << 10)); // [33.5,34) 512KB

  prep<<<512, 256, 0, stream>>>(w_qkv, w_proj, w_mlp1, w_mlp2, wq, wp, w1, w2,
                                x, ln1_g, ln1_b, xl, xn);

  // qkv: RPW=16 (R7 config), 768 blocks
  gemm_bt<256, 3, 16><<<dim3(64, 12), 256, 0, stream>>>(xn, wq, b_qkv, qkvh, 768);
  attn_split<<<256 * SPLIT, 256, 0, stream>>>(qkvh, o_part, l_part);
  attn_norm<<<512, 256, 0, stream>>>(o_part, l_part, attn);

  // proj: K-split x2 streaming fp32 partials (512 blocks)
  gemm_bt<256, 4, 16, 2><<<dim3(64, 4, 2), 256, 0, stream>>>(attn, wp, nullptr, pp, 256);
  combine_ln<<<1024, 256, 0, stream>>>(pp, xl, b_proj, ln2_g, ln2_b, xl2, xn2);

  // mlp1: RPW=16, 1024 blocks
  gemm_bt<256, 1, 16><<<dim3(64, 16), 256, 0, stream>>>(xn2, w1, b_mlp1, h1, 1024);
  // mlp2: RPW=16 + K-split x4, 1024 blocks
  gemm_bt<1024, 4, 16, 4><<<dim3(64, 4, 4), 256, 0, stream>>>(h1, w2, nullptr, mp, 256);
  combine_transpose<<<dim3(128, 8), 256, 0, stream>>>(mp, xl2, b_mlp2, (float*)d_out);
}